// Round 6
// baseline (159.757 us; speedup 1.0000x reference)
//
#include <hip/hip_runtime.h>
#include <math.h>

// Problem constants (fixed by the reference setup_inputs).
#define N 8192
#define D 64
#define C 100
#define T 30
#define GSTRIDE 32   // padded leading dim of per-class Gram rows
#define ZROWS 32     // z0 rows padded 30 -> 32 for MFMA u-tiles
#define CROWS 112    // W^T rows padded 100 -> 112 (7 MFMA c-tiles)
#define WSTRIDE 20   // per-wave transpose row stride (16 u's + 4 pad)
#define SB 16        // epilogue samples per block

static constexpr float D_LOG_2PI      = 117.62413225019811f; // D * log(2*pi)
static constexpr float EV_BUDGET_F    = 80.992775903017304f; // 0.5 * D * log(4*pi)
static constexpr float LOG_EV_CLAMP_F = 10.0f;

typedef __attribute__((ext_vector_type(8))) short short8x;   // 8 x bf16 bits
typedef __attribute__((ext_vector_type(4))) float floatx4;   // MFMA C/D frag

static __device__ __forceinline__ unsigned short f2bf(float f) {
    __bf16 h = (__bf16)f;                       // RNE convert
    return __builtin_bit_cast(unsigned short, h);
}

// Scalar (SMEM) load of block-uniform data: integer-intermediate cast to
// addrspace(4) (CK's cast_pointer_to_constant_address_space). Uniform
// address -> s_load_dwordx4; consumers read SGPRs (free operand in VALU).
#define AS_CONST __attribute__((address_space(4)))
typedef const AS_CONST floatx4* cfp4_t;
static __device__ __forceinline__ floatx4 sload4(const float* p) {
    return *(cfp4_t)(unsigned long long)p;
}

// ---------------------------------------------------------------------------
// Kernel MP: merged prep (one launch). Writes packed abgt[c][t] =
// (alpha, beta, Gtt, 0); zero-fills Gram pad columns 30..31.
// ---------------------------------------------------------------------------
__global__ __launch_bounds__(256) void megaprep_kernel(
        const float* __restrict__ x,
        const float* __restrict__ z0,
        const float* __restrict__ ap,
        const float* __restrict__ bp,
        const float* __restrict__ W,
        unsigned short* __restrict__ xbf,
        float* __restrict__ q0,
        float* __restrict__ Gp,
        float* __restrict__ abgt,
        unsigned short* __restrict__ z0bf,
        unsigned short* __restrict__ wtbf) {
    const int blk = blockIdx.x;

    if (blk < 256) {                         // ---- xprep ----
        const int r = blk * 32 + (threadIdx.x >> 3);
        const int e = threadIdx.x & 7;
        const float4* xp = (const float4*)(x + (size_t)r * D + e * 8);
        const float4 a = xp[0], b = xp[1];
        short8x o;
        o[0] = f2bf(a.x); o[1] = f2bf(a.y); o[2] = f2bf(a.z); o[3] = f2bf(a.w);
        o[4] = f2bf(b.x); o[5] = f2bf(b.y); o[6] = f2bf(b.z); o[7] = f2bf(b.w);
        *(short8x*)(xbf + (size_t)r * D + e * 8) = o;
        float q = a.x*a.x + a.y*a.y + a.z*a.z + a.w*a.w
                + b.x*b.x + b.y*b.y + b.z*b.z + b.w*b.w;
        q += __shfl_xor(q, 4, 8);
        q += __shfl_xor(q, 2, 8);
        q += __shfl_xor(q, 1, 8);
        if (e == 0) q0[r] = q;
        return;
    }

    if (blk >= 356) {                        // ---- wprep ----
        const int i = (blk - 356) * 256 + threadIdx.x;   // covers CROWS*D
        const int c = i >> 6, d = i & 63;
        wtbf[i] = f2bf(c < C ? W[d * C + c] : 0.0f);
        return;
    }

    // ---- class prep ----
    const int c = blk - 256;
    __shared__ float z0s[T * D];
    for (int i = threadIdx.x; i < T * D; i += blockDim.x)
        z0s[i] = z0[c * T * D + i];
    __syncthreads();

    for (int idx = threadIdx.x; idx < T * GSTRIDE; idx += blockDim.x) {
        const int u = idx >> 5, v = idx & 31;
        float s = 0.0f;
        if (v < T) {
            #pragma unroll
            for (int d = 0; d < D; ++d)
                s = fmaf(z0s[u * D + d], z0s[v * D + d], s);
        }
        Gp[(size_t)c * T * GSTRIDE + idx] = s;
    }

    for (int i = threadIdx.x; i < ZROWS * D; i += blockDim.x) {
        const int u = i >> 6;
        z0bf[(size_t)c * ZROWS * D + i] = f2bf(u < T ? z0s[u * D + (i & 63)] : 0.0f);
    }

    if (threadIdx.x < T) {
        const int t = threadIdx.x;
        const float a = ap[c * T + t];
        const float b = bp[c * T + t];
        const float spa = fmaxf(a, 0.0f) + log1pf(expf(-fabsf(a)));
        const float spb = fmaxf(b, 0.0f) + log1pf(expf(-fabsf(b)));
        float gtt = 0.0f;
        #pragma unroll
        for (int d = 0; d < D; ++d)
            gtt = fmaf(z0s[t * D + d], z0s[t * D + d], gtt);
        float* o = abgt + ((size_t)c * T + t) * 4;
        o[0] = spa;
        o[1] = -spa + spb;
        o[2] = gtt;
        o[3] = 0.0f;
    }
}

// ---------------------------------------------------------------------------
// Kernel A: flow, R15 == R14 resubmit (R14 bench was an infra flake; the
// only delta vs the PASSING R13 was launch_bounds (256,2)->(256,3), which
// is legal and cannot fail deterministically).
// R13 post-mortem: the (256,2) bound let the allocator target 4 waves/SIMD
// (128 VGPR) and SPILL ~8 dw/thread into the recurrence (WRITE_SIZE 9.7MB
// vs 3.2 ideal); scratch reload latency in the inner loop kept VALUBusy at
// 33%. Live set in phase 2 is ~150-160 (w[4][32]=128 + q/P/pf/pg/nk +
// addr) < 170 -> zero spill at 3 waves/SIMD residency, which covers the
// whole grid (3.125 waves/SIMD) and gives 12 independent chains per SIMD
// to hide the ~60cyc/t serial chain. Issue-bound floor ~11us for phase 2.
// REGISTER-BUDGET HISTORY (do not regress):
//   cap128 (R5/R6/R13): spills (72/72/8 dw). cap170 R7 (old structure):
//   13 dw. (256,2) R9/R11: zero spill at 84/68 (no pressure). R15: live
//   ~155 under cap 170 -> expect zero.
//   WRITE_SIZE == 3200 KB is the no-spill sentinel; watch it.
// ---------------------------------------------------------------------------
__global__ __launch_bounds__(256, 3) void flow_kernel(
        const unsigned short* __restrict__ xbf,
        const float* __restrict__ q0g,
        const unsigned short* __restrict__ z0bf,
        const float* __restrict__ Gp,
        const float* __restrict__ abgt,
        float* __restrict__ lp) {
    const int c    = blockIdx.y;
    const int wv   = threadIdx.x >> 6;
    const int ln   = threadIdx.x & 63;
    const int col  = ln & 15;
    const int quad = ln >> 4;
    const int nb   = blockIdx.x * 1024 + wv * 256;  // wave's 256-sample base

    __shared__ float wlds[4][64 * WSTRIDE];  // 20480 B

    const float* gb = Gp + (size_t)c * T * GSTRIDE;
    const float* ab = abgt + ((size_t)c * T) * 4;

    // ---- L2 warm-up prefetch: whole class G (240 float4) + abgt (30) ----
    {
        const float4* gpre = (const float4*)gb;
        const int gi = threadIdx.x < 240 ? threadIdx.x : 239;
        const float4 d0 = gpre[gi];
        const float4* apre = (const float4*)ab;
        const int ai = (threadIdx.x & 31) < 30 ? (threadIdx.x & 31) : 29;
        const float4 d1 = apre[ai];
        asm volatile("" :: "v"(d0.x), "v"(d1.x));   // keep alive, then dead
    }

    // ---- Phase 1: MFMA, 4 halves x 2 mu; A frags hoisted (shared) ----
    const unsigned short* zb = z0bf + (size_t)c * ZROWS * D;
    short8x A[2][2];
    #pragma unroll
    for (int mu = 0; mu < 2; ++mu) {
        A[mu][0] = *(const short8x*)(zb + (mu * 16 + col) * D + quad * 8);
        A[mu][1] = *(const short8x*)(zb + (mu * 16 + col) * D + 32 + quad * 8);
    }

    float w[4][ZROWS];
    #pragma unroll
    for (int half = 0; half < 4; ++half) {
        const int hb = nb + half * 64;
        #pragma unroll
        for (int mu = 0; mu < 2; ++mu) {
            floatx4 acc[4];
            #pragma unroll
            for (int nt = 0; nt < 4; ++nt) acc[nt] = (floatx4)(0.0f);
            #pragma unroll
            for (int nt = 0; nt < 4; ++nt) {
                const unsigned short* bp_ =
                    xbf + (size_t)(hb + nt * 16 + col) * D + quad * 8;
                const short8x B0 = *(const short8x*)(bp_);
                acc[nt] = __builtin_amdgcn_mfma_f32_16x16x32_bf16(A[mu][0], B0, acc[nt], 0, 0, 0);
                const short8x B1 = *(const short8x*)(bp_ + 32);
                acc[nt] = __builtin_amdgcn_mfma_f32_16x16x32_bf16(A[mu][1], B1, acc[nt], 0, 0, 0);
            }
            // per-wave transpose through LDS (same-wave lockstep, no barrier)
            #pragma unroll
            for (int nt = 0; nt < 4; ++nt)
                *(floatx4*)&wlds[wv][(nt * 16 + col) * WSTRIDE + quad * 4] = acc[nt];
            #pragma unroll
            for (int j = 0; j < 4; ++j) {
                const float4 t = *(const float4*)&wlds[wv][ln * WSTRIDE + j * 4];
                w[half][mu * 16 + 4 * j + 0] = t.x;
                w[half][mu * 16 + 4 * j + 1] = t.y;
                w[half][mu * 16 + 4 * j + 2] = t.z;
                w[half][mu * 16 + 4 * j + 3] = t.w;
            }
        }
    }

    // ---- Phase 2: quad-sample Gram-trick recurrence, scalar-fed ----
    float q[4], P[4], pf[4], pg[4];
    #pragma unroll
    for (int s = 0; s < 4; ++s) {
        q[s]  = q0g[nb + s * 64 + ln];
        P[s]  = 1.0f;
        pf[s] = 1.0f;   // prod of f
        pg[s] = 1.0f;   // prod of (1 + bh*alpha*h)
    }

    #pragma unroll
    for (int t = 0; t < T; ++t) {
        const floatx4 av = sload4(ab + t * 4);     // s_load_dwordx4
        const float alpha = av[0], beta = av[1], Gtt = av[2];

        float nk[4];
        #pragma unroll
        for (int s = 0; s < 4; ++s) {              // 4 independent chains
            const float wt = P[s] * w[s][t];
            float r2 = fmaf(-2.0f, wt, q[s]) + Gtt;
            r2 = fmaxf(r2, 0.0f);
            const float r  = __builtin_amdgcn_sqrtf(r2);
            const float h  = __builtin_amdgcn_rcpf(alpha + r);
            const float bh = beta * h;
            const float f  = 1.0f + bh;
            pf[s] *= f;
            pg[s] *= fmaf(bh * alpha, h, 1.0f);
            float qn = f * f * q[s];
            qn = fmaf(bh * f, -2.0f * wt, qn);
            qn = fmaf(bh * bh, Gtt, qn);
            q[s] = qn;
            const float Pn = P[s] * f;
            nk[s] = -(bh * __builtin_amdgcn_rcpf(Pn));
            P[s] = Pn;
        }

        // joint w-update: one SCALAR G float4 feeds all 4 samples (16 FMA,
        // SGPR broadcast operand per v_fma)
        #pragma unroll
        for (int m4 = 0; m4 < 8; ++m4) {
            if (m4 < (t >> 2)) continue;          // blocks fully in the past
            const floatx4 g = sload4(gb + t * GSTRIDE + 4 * m4);
            #pragma unroll
            for (int s = 0; s < 4; ++s) {
                w[s][4 * m4 + 0] = fmaf(nk[s], g[0], w[s][4 * m4 + 0]);
                w[s][4 * m4 + 1] = fmaf(nk[s], g[1], w[s][4 * m4 + 1]);
                w[s][4 * m4 + 2] = fmaf(nk[s], g[2], w[s][4 * m4 + 2]);
                w[s][4 * m4 + 3] = fmaf(nk[s], g[3], w[s][4 * m4 + 3]);
            }
        }
    }

    #pragma unroll
    for (int s = 0; s < 4; ++s) {
        const float ld = 63.0f * __logf(pf[s]) + __logf(pg[s]);
        lp[(size_t)c * N + nb + s * 64 + ln] = -0.5f * (D_LOG_2PI + q[s]) + ld;
    }
}

// ---------------------------------------------------------------------------
// Kernel C: epilogue with MFMA-fused logits. Unchanged (verified).
// ---------------------------------------------------------------------------
__global__ __launch_bounds__(256) void epilogue_kernel(
        const float* __restrict__ lp,
        const unsigned short* __restrict__ xbf,
        const unsigned short* __restrict__ wtbf,
        const float* __restrict__ b,
        const int* __restrict__ labels,
        const float* __restrict__ freq,
        float* __restrict__ out) {
    const int n0  = blockIdx.x * SB;
    const int tid = threadIdx.x;
    const int wv  = tid >> 6;
    const int ln  = tid & 63;

    __shared__ float lps[SB][101];   // pad 101
    __shared__ float lgs[SB][CROWS]; // raw logits (bias added later)
    __shared__ float lf[C];
    __shared__ float bsm[C];
    __shared__ int   lbl[SB];

    if (wv == 0) {
        // ---- logits via MFMA: A = W^T tile (m=c), B = x (col=n) ----
        const int col  = ln & 15;
        const int quad = ln >> 4;
        const unsigned short* bp_ = xbf + (size_t)(n0 + col) * D + quad * 8;
        const short8x B0 = *(const short8x*)(bp_);
        const short8x B1 = *(const short8x*)(bp_ + 32);
        #pragma unroll
        for (int ct = 0; ct < 7; ++ct) {
            const unsigned short* apq = wtbf + (size_t)(ct * 16 + col) * D + quad * 8;
            const short8x A0 = *(const short8x*)(apq);
            const short8x A1 = *(const short8x*)(apq + 32);
            floatx4 acc = (floatx4)(0.0f);
            acc = __builtin_amdgcn_mfma_f32_16x16x32_bf16(A0, B0, acc, 0, 0, 0);
            acc = __builtin_amdgcn_mfma_f32_16x16x32_bf16(A1, B1, acc, 0, 0, 0);
            #pragma unroll
            for (int j = 0; j < 4; ++j)       // C/D: row=quad*4+j (class), col=n
                lgs[col][ct * 16 + quad * 4 + j] = acc[j];
        }
    } else {
        // ---- waves 1-3: stage lp tile (1600 floats), coalesced 16-runs ----
        for (int i = tid - 64; i < C * SB; i += 192) {
            const int cc = i >> 4, s = i & (SB - 1);
            lps[s][cc] = lp[(size_t)cc * N + n0 + s];
        }
        // lf/bsm: threads 64..163 cover all C=100 entries
        if (tid - 64 < C) {
            const int t2 = tid - 64;
            lf[t2]  = __logf(freq[t2]);
            bsm[t2] = b[t2];
        }
        // lbl: threads 192..207 cover SB=16 entries
        if (tid >= 192 && tid < 192 + SB)
            lbl[tid - 192] = labels[n0 + (tid - 192)];
    }
    __syncthreads();

    const int s = tid >> 4;          // sample in tile (16-groups in-wave)
    const int k = tid & 15;          // lane within sample group
    const int n = n0 + s;

    float lgt[7];
    float lm = -INFINITY;
    float vm = -INFINITY, vs = 0.0f;   // online logsumexp partial (lp+lf)
    #pragma unroll
    for (int j = 0; j < 7; ++j) {
        const int cc = k + 16 * j;
        if (cc < C) {
            const float v = lps[s][cc] + lf[cc];
            const float m2 = fmaxf(vm, v);
            vs = vs * __expf(vm - m2) + __expf(v - m2);
            vm = m2;
            lgt[j] = lgs[s][cc] + bsm[cc];
            lm = fmaxf(lm, lgt[j]);
        } else lgt[j] = -INFINITY;
    }

    #pragma unroll
    for (int off = 8; off >= 1; off >>= 1) {
        const float om = __shfl_xor(vm, off, 16);
        const float os = __shfl_xor(vs, off, 16);
        const float m2 = fmaxf(vm, om);
        vs = vs * __expf(vm - m2) + os * __expf(om - m2);
        vm = m2;
        lm = fmaxf(lm, __shfl_xor(lm, off, 16));
    }
    const float marg = vm + __logf(vs);
    const float ev = __expf(fminf(marg + EV_BUDGET_F, LOG_EV_CLAMP_F));

    float ls = 0.0f;
    #pragma unroll
    for (int j = 0; j < 7; ++j)
        if (k + 16 * j < C) ls += __expf(lgt[j] - lm);
    #pragma unroll
    for (int off = 8; off >= 1; off >>= 1)
        ls += __shfl_xor(ls, off, 16);

    const float inv = ev / ls;
    float* __restrict__ outr = out + (size_t)n * (C + 1);
    #pragma unroll
    for (int j = 0; j < 7; ++j) {
        const int cc = k + 16 * j;
        if (cc < C) outr[cc] = log1pf(__expf(lgt[j] - lm) * inv);
    }
    if (k == 0) outr[C] = lps[s][lbl[s]];
}

// ---------------------------------------------------------------------------
extern "C" void kernel_launch(void* const* d_in, const int* in_sizes, int n_in,
                              void* d_out, int out_size, void* d_ws, size_t ws_size,
                              hipStream_t stream) {
    const float* x      = (const float*)d_in[0];
    const int*   labels = (const int*)  d_in[1];
    const float* freq   = (const float*)d_in[2];
    const float* z0     = (const float*)d_in[3];
    const float* ap     = (const float*)d_in[4];
    const float* bp     = (const float*)d_in[5];
    const float* W      = (const float*)d_in[6];
    const float* b      = (const float*)d_in[7];
    float* out = (float*)d_out;

    // Workspace (floats): lp[C*N] | Gp | abgt | z0bf | xbf | wtbf | q0
    float* ws     = (float*)d_ws;
    float* lp     = ws;
    float* Gp     = lp + (size_t)C * N;
    float* abgt   = Gp + (size_t)C * T * GSTRIDE;
    unsigned short* z0bf = (unsigned short*)(abgt + (size_t)C * T * 4);
    unsigned short* xbf  = z0bf + (size_t)C * ZROWS * D;
    unsigned short* wtbf = xbf + (size_t)N * D;
    float* q0     = (float*)(wtbf + (size_t)CROWS * D);

    megaprep_kernel<<<384, 256, 0, stream>>>(x, z0, ap, bp, W,
                                             xbf, q0, Gp, abgt, z0bf, wtbf);
    flow_kernel<<<dim3(N / 1024, C), 256, 0, stream>>>(xbf, q0, z0bf, Gp, abgt, lp);
    epilogue_kernel<<<N / SB, 256, 0, stream>>>(lp, xbf, wtbf, b, labels, freq, out);
}

// Round 7
// 134.622 us; speedup vs baseline: 1.1867x; 1.1867x over previous
//
#include <hip/hip_runtime.h>
#include <math.h>

// Problem constants (fixed by the reference setup_inputs).
#define N 8192
#define D 64
#define C 100
#define T 30
#define GSTRIDE 32   // padded leading dim of per-class Gram rows
#define ZROWS 32     // z0 rows padded 30 -> 32 for MFMA u-tiles
#define CROWS 112    // W^T rows padded 100 -> 112 (7 MFMA c-tiles)
#define WSTRIDE 20   // per-wave transpose row stride (16 u's + 4 pad)
#define SB 16        // epilogue samples per block

static constexpr float D_LOG_2PI      = 117.62413225019811f; // D * log(2*pi)
static constexpr float EV_BUDGET_F    = 80.992775903017304f; // 0.5 * D * log(4*pi)
static constexpr float LOG_EV_CLAMP_F = 10.0f;

typedef __attribute__((ext_vector_type(8))) short short8x;   // 8 x bf16 bits
typedef __attribute__((ext_vector_type(4))) float floatx4;   // MFMA C/D frag

static __device__ __forceinline__ unsigned short f2bf(float f) {
    __bf16 h = (__bf16)f;                       // RNE convert
    return __builtin_bit_cast(unsigned short, h);
}

// Scalar (SMEM) load of block-uniform data: integer-intermediate cast to
// addrspace(4) (CK's cast_pointer_to_constant_address_space). Uniform
// address -> s_load_dwordx4; consumers read SGPRs (free operand in VALU).
#define AS_CONST __attribute__((address_space(4)))
typedef const AS_CONST floatx4* cfp4_t;
static __device__ __forceinline__ floatx4 sload4(const float* p) {
    return *(cfp4_t)(unsigned long long)p;
}

// ---------------------------------------------------------------------------
// Kernel MP: merged prep (one launch). Writes packed abgt[c][t] =
// (alpha, beta, Gtt, 0); zero-fills Gram pad columns 30..31.
// ---------------------------------------------------------------------------
__global__ __launch_bounds__(256) void megaprep_kernel(
        const float* __restrict__ x,
        const float* __restrict__ z0,
        const float* __restrict__ ap,
        const float* __restrict__ bp,
        const float* __restrict__ W,
        unsigned short* __restrict__ xbf,
        float* __restrict__ q0,
        float* __restrict__ Gp,
        float* __restrict__ abgt,
        unsigned short* __restrict__ z0bf,
        unsigned short* __restrict__ wtbf) {
    const int blk = blockIdx.x;

    if (blk < 256) {                         // ---- xprep ----
        const int r = blk * 32 + (threadIdx.x >> 3);
        const int e = threadIdx.x & 7;
        const float4* xp = (const float4*)(x + (size_t)r * D + e * 8);
        const float4 a = xp[0], b = xp[1];
        short8x o;
        o[0] = f2bf(a.x); o[1] = f2bf(a.y); o[2] = f2bf(a.z); o[3] = f2bf(a.w);
        o[4] = f2bf(b.x); o[5] = f2bf(b.y); o[6] = f2bf(b.z); o[7] = f2bf(b.w);
        *(short8x*)(xbf + (size_t)r * D + e * 8) = o;
        float q = a.x*a.x + a.y*a.y + a.z*a.z + a.w*a.w
                + b.x*b.x + b.y*b.y + b.z*b.z + b.w*b.w;
        q += __shfl_xor(q, 4, 8);
        q += __shfl_xor(q, 2, 8);
        q += __shfl_xor(q, 1, 8);
        if (e == 0) q0[r] = q;
        return;
    }

    if (blk >= 356) {                        // ---- wprep ----
        const int i = (blk - 356) * 256 + threadIdx.x;   // covers CROWS*D
        const int c = i >> 6, d = i & 63;
        wtbf[i] = f2bf(c < C ? W[d * C + c] : 0.0f);
        return;
    }

    // ---- class prep ----
    const int c = blk - 256;
    __shared__ float z0s[T * D];
    for (int i = threadIdx.x; i < T * D; i += blockDim.x)
        z0s[i] = z0[c * T * D + i];
    __syncthreads();

    for (int idx = threadIdx.x; idx < T * GSTRIDE; idx += blockDim.x) {
        const int u = idx >> 5, v = idx & 31;
        float s = 0.0f;
        if (v < T) {
            #pragma unroll
            for (int d = 0; d < D; ++d)
                s = fmaf(z0s[u * D + d], z0s[v * D + d], s);
        }
        Gp[(size_t)c * T * GSTRIDE + idx] = s;
    }

    for (int i = threadIdx.x; i < ZROWS * D; i += blockDim.x) {
        const int u = i >> 6;
        z0bf[(size_t)c * ZROWS * D + i] = f2bf(u < T ? z0s[u * D + (i & 63)] : 0.0f);
    }

    if (threadIdx.x < T) {
        const int t = threadIdx.x;
        const float a = ap[c * T + t];
        const float b = bp[c * T + t];
        const float spa = fmaxf(a, 0.0f) + log1pf(expf(-fabsf(a)));
        const float spb = fmaxf(b, 0.0f) + log1pf(expf(-fabsf(b)));
        float gtt = 0.0f;
        #pragma unroll
        for (int d = 0; d < D; ++d)
            gtt = fmaf(z0s[t * D + d], z0s[t * D + d], gtt);
        float* o = abgt + ((size_t)c * T + t) * 4;
        o[0] = spa;
        o[1] = -spa + spb;
        o[2] = gtt;
        o[3] = 0.0f;
    }
}

// ---------------------------------------------------------------------------
// Kernel A: flow, R16 = R13 body + amdgpu_waves_per_eu(2,2).
// ALLOCATOR HISTORY (the whole story, do not regress):
//   R13 (256,2): allocator OPPORTUNISTICALLY shrank to 128 VGPR to reach 4
//     waves/SIMD, spilling ~8 dw/thread (WRITE_SIZE 9.7MB) -> 49.4us.
//   R15 (256,3): worse heuristic corner - 84 VGPR, ~80MB scratch writes,
//     75us. The min-waves hint does NOT stop spill-for-occupancy trades.
//   R16: waves_per_eu(2,2) sets MAX=2 -> no benefit to shrinking below 256
//     VGPRs -> live set (~155: w[4][32]=128 + q/P/pf/pg/nk + addr) fits
//     with ZERO spill. 2 waves/SIMD x 4 chains = 8 independent chains/SIMD
//     hide the ~60cyc/t serial recurrence. Phase-2 issue floor ~11-16us.
//   WRITE_SIZE == 3200 KB is the no-spill sentinel; THE validation number.
// ---------------------------------------------------------------------------
__global__ void __launch_bounds__(256)
__attribute__((amdgpu_waves_per_eu(2, 2)))
flow_kernel(
        const unsigned short* __restrict__ xbf,
        const float* __restrict__ q0g,
        const unsigned short* __restrict__ z0bf,
        const float* __restrict__ Gp,
        const float* __restrict__ abgt,
        float* __restrict__ lp) {
    const int c    = blockIdx.y;
    const int wv   = threadIdx.x >> 6;
    const int ln   = threadIdx.x & 63;
    const int col  = ln & 15;
    const int quad = ln >> 4;
    const int nb   = blockIdx.x * 1024 + wv * 256;  // wave's 256-sample base

    __shared__ float wlds[4][64 * WSTRIDE];  // 20480 B

    const float* gb = Gp + (size_t)c * T * GSTRIDE;
    const float* ab = abgt + ((size_t)c * T) * 4;

    // ---- L2 warm-up prefetch: whole class G (240 float4) + abgt (30) ----
    {
        const float4* gpre = (const float4*)gb;
        const int gi = threadIdx.x < 240 ? threadIdx.x : 239;
        const float4 d0 = gpre[gi];
        const float4* apre = (const float4*)ab;
        const int ai = (threadIdx.x & 31) < 30 ? (threadIdx.x & 31) : 29;
        const float4 d1 = apre[ai];
        asm volatile("" :: "v"(d0.x), "v"(d1.x));   // keep alive, then dead
    }

    // ---- Phase 1: MFMA, 4 halves x 2 mu; A frags hoisted (shared) ----
    const unsigned short* zb = z0bf + (size_t)c * ZROWS * D;
    short8x A[2][2];
    #pragma unroll
    for (int mu = 0; mu < 2; ++mu) {
        A[mu][0] = *(const short8x*)(zb + (mu * 16 + col) * D + quad * 8);
        A[mu][1] = *(const short8x*)(zb + (mu * 16 + col) * D + 32 + quad * 8);
    }

    float w[4][ZROWS];
    #pragma unroll
    for (int half = 0; half < 4; ++half) {
        const int hb = nb + half * 64;
        #pragma unroll
        for (int mu = 0; mu < 2; ++mu) {
            floatx4 acc[4];
            #pragma unroll
            for (int nt = 0; nt < 4; ++nt) acc[nt] = (floatx4)(0.0f);
            #pragma unroll
            for (int nt = 0; nt < 4; ++nt) {
                const unsigned short* bp_ =
                    xbf + (size_t)(hb + nt * 16 + col) * D + quad * 8;
                const short8x B0 = *(const short8x*)(bp_);
                acc[nt] = __builtin_amdgcn_mfma_f32_16x16x32_bf16(A[mu][0], B0, acc[nt], 0, 0, 0);
                const short8x B1 = *(const short8x*)(bp_ + 32);
                acc[nt] = __builtin_amdgcn_mfma_f32_16x16x32_bf16(A[mu][1], B1, acc[nt], 0, 0, 0);
            }
            // per-wave transpose through LDS (same-wave lockstep, no barrier)
            #pragma unroll
            for (int nt = 0; nt < 4; ++nt)
                *(floatx4*)&wlds[wv][(nt * 16 + col) * WSTRIDE + quad * 4] = acc[nt];
            #pragma unroll
            for (int j = 0; j < 4; ++j) {
                const float4 t = *(const float4*)&wlds[wv][ln * WSTRIDE + j * 4];
                w[half][mu * 16 + 4 * j + 0] = t.x;
                w[half][mu * 16 + 4 * j + 1] = t.y;
                w[half][mu * 16 + 4 * j + 2] = t.z;
                w[half][mu * 16 + 4 * j + 3] = t.w;
            }
        }
    }

    // ---- Phase 2: quad-sample Gram-trick recurrence, scalar-fed ----
    float q[4], P[4], pf[4], pg[4];
    #pragma unroll
    for (int s = 0; s < 4; ++s) {
        q[s]  = q0g[nb + s * 64 + ln];
        P[s]  = 1.0f;
        pf[s] = 1.0f;   // prod of f
        pg[s] = 1.0f;   // prod of (1 + bh*alpha*h)
    }

    #pragma unroll
    for (int t = 0; t < T; ++t) {
        const floatx4 av = sload4(ab + t * 4);     // s_load_dwordx4
        const float alpha = av[0], beta = av[1], Gtt = av[2];

        float nk[4];
        #pragma unroll
        for (int s = 0; s < 4; ++s) {              // 4 independent chains
            const float wt = P[s] * w[s][t];
            float r2 = fmaf(-2.0f, wt, q[s]) + Gtt;
            r2 = fmaxf(r2, 0.0f);
            const float r  = __builtin_amdgcn_sqrtf(r2);
            const float h  = __builtin_amdgcn_rcpf(alpha + r);
            const float bh = beta * h;
            const float f  = 1.0f + bh;
            pf[s] *= f;
            pg[s] *= fmaf(bh * alpha, h, 1.0f);
            float qn = f * f * q[s];
            qn = fmaf(bh * f, -2.0f * wt, qn);
            qn = fmaf(bh * bh, Gtt, qn);
            q[s] = qn;
            const float Pn = P[s] * f;
            nk[s] = -(bh * __builtin_amdgcn_rcpf(Pn));
            P[s] = Pn;
        }

        // joint w-update: one SCALAR G float4 feeds all 4 samples (16 FMA,
        // SGPR broadcast operand per v_fma)
        #pragma unroll
        for (int m4 = 0; m4 < 8; ++m4) {
            if (m4 < (t >> 2)) continue;          // blocks fully in the past
            const floatx4 g = sload4(gb + t * GSTRIDE + 4 * m4);
            #pragma unroll
            for (int s = 0; s < 4; ++s) {
                w[s][4 * m4 + 0] = fmaf(nk[s], g[0], w[s][4 * m4 + 0]);
                w[s][4 * m4 + 1] = fmaf(nk[s], g[1], w[s][4 * m4 + 1]);
                w[s][4 * m4 + 2] = fmaf(nk[s], g[2], w[s][4 * m4 + 2]);
                w[s][4 * m4 + 3] = fmaf(nk[s], g[3], w[s][4 * m4 + 3]);
            }
        }
    }

    #pragma unroll
    for (int s = 0; s < 4; ++s) {
        const float ld = 63.0f * __logf(pf[s]) + __logf(pg[s]);
        lp[(size_t)c * N + nb + s * 64 + ln] = -0.5f * (D_LOG_2PI + q[s]) + ld;
    }
}

// ---------------------------------------------------------------------------
// Kernel C: epilogue with MFMA-fused logits. Unchanged (verified).
// ---------------------------------------------------------------------------
__global__ __launch_bounds__(256) void epilogue_kernel(
        const float* __restrict__ lp,
        const unsigned short* __restrict__ xbf,
        const unsigned short* __restrict__ wtbf,
        const float* __restrict__ b,
        const int* __restrict__ labels,
        const float* __restrict__ freq,
        float* __restrict__ out) {
    const int n0  = blockIdx.x * SB;
    const int tid = threadIdx.x;
    const int wv  = tid >> 6;
    const int ln  = tid & 63;

    __shared__ float lps[SB][101];   // pad 101
    __shared__ float lgs[SB][CROWS]; // raw logits (bias added later)
    __shared__ float lf[C];
    __shared__ float bsm[C];
    __shared__ int   lbl[SB];

    if (wv == 0) {
        // ---- logits via MFMA: A = W^T tile (m=c), B = x (col=n) ----
        const int col  = ln & 15;
        const int quad = ln >> 4;
        const unsigned short* bp_ = xbf + (size_t)(n0 + col) * D + quad * 8;
        const short8x B0 = *(const short8x*)(bp_);
        const short8x B1 = *(const short8x*)(bp_ + 32);
        #pragma unroll
        for (int ct = 0; ct < 7; ++ct) {
            const unsigned short* apq = wtbf + (size_t)(ct * 16 + col) * D + quad * 8;
            const short8x A0 = *(const short8x*)(apq);
            const short8x A1 = *(const short8x*)(apq + 32);
            floatx4 acc = (floatx4)(0.0f);
            acc = __builtin_amdgcn_mfma_f32_16x16x32_bf16(A0, B0, acc, 0, 0, 0);
            acc = __builtin_amdgcn_mfma_f32_16x16x32_bf16(A1, B1, acc, 0, 0, 0);
            #pragma unroll
            for (int j = 0; j < 4; ++j)       // C/D: row=quad*4+j (class), col=n
                lgs[col][ct * 16 + quad * 4 + j] = acc[j];
        }
    } else {
        // ---- waves 1-3: stage lp tile (1600 floats), coalesced 16-runs ----
        for (int i = tid - 64; i < C * SB; i += 192) {
            const int cc = i >> 4, s = i & (SB - 1);
            lps[s][cc] = lp[(size_t)cc * N + n0 + s];
        }
        // lf/bsm: threads 64..163 cover all C=100 entries
        if (tid - 64 < C) {
            const int t2 = tid - 64;
            lf[t2]  = __logf(freq[t2]);
            bsm[t2] = b[t2];
        }
        // lbl: threads 192..207 cover SB=16 entries
        if (tid >= 192 && tid < 192 + SB)
            lbl[tid - 192] = labels[n0 + (tid - 192)];
    }
    __syncthreads();

    const int s = tid >> 4;          // sample in tile (16-groups in-wave)
    const int k = tid & 15;          // lane within sample group
    const int n = n0 + s;

    float lgt[7];
    float lm = -INFINITY;
    float vm = -INFINITY, vs = 0.0f;   // online logsumexp partial (lp+lf)
    #pragma unroll
    for (int j = 0; j < 7; ++j) {
        const int cc = k + 16 * j;
        if (cc < C) {
            const float v = lps[s][cc] + lf[cc];
            const float m2 = fmaxf(vm, v);
            vs = vs * __expf(vm - m2) + __expf(v - m2);
            vm = m2;
            lgt[j] = lgs[s][cc] + bsm[cc];
            lm = fmaxf(lm, lgt[j]);
        } else lgt[j] = -INFINITY;
    }

    #pragma unroll
    for (int off = 8; off >= 1; off >>= 1) {
        const float om = __shfl_xor(vm, off, 16);
        const float os = __shfl_xor(vs, off, 16);
        const float m2 = fmaxf(vm, om);
        vs = vs * __expf(vm - m2) + os * __expf(om - m2);
        vm = m2;
        lm = fmaxf(lm, __shfl_xor(lm, off, 16));
    }
    const float marg = vm + __logf(vs);
    const float ev = __expf(fminf(marg + EV_BUDGET_F, LOG_EV_CLAMP_F));

    float ls = 0.0f;
    #pragma unroll
    for (int j = 0; j < 7; ++j)
        if (k + 16 * j < C) ls += __expf(lgt[j] - lm);
    #pragma unroll
    for (int off = 8; off >= 1; off >>= 1)
        ls += __shfl_xor(ls, off, 16);

    const float inv = ev / ls;
    float* __restrict__ outr = out + (size_t)n * (C + 1);
    #pragma unroll
    for (int j = 0; j < 7; ++j) {
        const int cc = k + 16 * j;
        if (cc < C) outr[cc] = log1pf(__expf(lgt[j] - lm) * inv);
    }
    if (k == 0) outr[C] = lps[s][lbl[s]];
}

// ---------------------------------------------------------------------------
extern "C" void kernel_launch(void* const* d_in, const int* in_sizes, int n_in,
                              void* d_out, int out_size, void* d_ws, size_t ws_size,
                              hipStream_t stream) {
    const float* x      = (const float*)d_in[0];
    const int*   labels = (const int*)  d_in[1];
    const float* freq   = (const float*)d_in[2];
    const float* z0     = (const float*)d_in[3];
    const float* ap     = (const float*)d_in[4];
    const float* bp     = (const float*)d_in[5];
    const float* W      = (const float*)d_in[6];
    const float* b      = (const float*)d_in[7];
    float* out = (float*)d_out;

    // Workspace (floats): lp[C*N] | Gp | abgt | z0bf | xbf | wtbf | q0
    float* ws     = (float*)d_ws;
    float* lp     = ws;
    float* Gp     = lp + (size_t)C * N;
    float* abgt   = Gp + (size_t)C * T * GSTRIDE;
    unsigned short* z0bf = (unsigned short*)(abgt + (size_t)C * T * 4);
    unsigned short* xbf  = z0bf + (size_t)C * ZROWS * D;
    unsigned short* wtbf = xbf + (size_t)N * D;
    float* q0     = (float*)(wtbf + (size_t)CROWS * D);

    megaprep_kernel<<<384, 256, 0, stream>>>(x, z0, ap, bp, W,
                                             xbf, q0, Gp, abgt, z0bf, wtbf);
    flow_kernel<<<dim3(N / 1024, C), 256, 0, stream>>>(xbf, q0, z0bf, Gp, abgt, lp);
    epilogue_kernel<<<N / SB, 256, 0, stream>>>(lp, xbf, wtbf, b, labels, freq, out);
}